// Round 13
// baseline (383.714 us; speedup 1.0000x reference)
//
#include <hip/hip_runtime.h>

typedef _Float16 h8 __attribute__((ext_vector_type(8)));
typedef float f4 __attribute__((ext_vector_type(4)));

#define MFMA16(a, b, c) __builtin_amdgcn_mfma_f32_16x16x32_f16((a), (b), (c), 0, 0, 0)

__device__ static inline void gl_lds16(const void* g, void* l) {
  __builtin_amdgcn_global_load_lds((const __attribute__((address_space(1))) unsigned int*)g,
                                   (__attribute__((address_space(3))) unsigned int*)l, 16, 0, 0);
}

// Monotone float<->uint encoding for atomicMax on floats (any sign).
__device__ static inline unsigned encf(float f) {
  unsigned u = __float_as_uint(f);
  return (u & 0x80000000u) ? ~u : (u | 0x80000000u);
}
__device__ static inline float decf(unsigned u) {
  return __uint_as_float((u & 0x80000000u) ? (u ^ 0x80000000u) : ~u);
}

// B=4, S=4096, D=512.
// IMG block = 16KB = 128 rows x 64 k fp16; half-offset(r,k) = r*64 + ((((k>>3)&7)^(r&7))<<3) + (k&7).
//  Qimg/Kimg: block(b, rb=s>>7, kc=d>>6) at ((b*32+rb)*8+kc)*16KB        [16MB each]
//  Ximg:      same layout as Qimg (fp16 pre-swizzled x)                  [16MB]
//  VTimg:     block(b, rb=d>>7, kc=s>>6) at ((b*4+rb)*64+kc)*16KB        [16MB]
//  Wt:        block(z, rb=n>>7, kc=k>>6) at ((z*4+rb)*8+kc)*16KB         [1.5MB]
//  Simg(chunk): block(rbL, kc=t>>6) at (rbL*64+kc)*16KB
// Round-13: pv B-LDS path deleted. sB was a verbatim copy of the VT img block, so
// B fragments are read DIRECTLY from VTimg (same offsets, same bytes). Removes the
// 8 gl_lds + 64KB LDS writes + per-iter vmcnt(0) drain; waves de-lockstep so B-load
// latency hides under other waves' MFMA. LDS shrinks to sA dbuf 16KB.

// ---------------- weight convert (+ mEnc zero) ----------------
__global__ void wconv_kernel(const float* __restrict__ Wq, const float* __restrict__ Wk,
                             const float* __restrict__ Wv, _Float16* __restrict__ Wt,
                             unsigned* __restrict__ mEnc) {
  int idx = blockIdx.x * 256 + threadIdx.x;
  if (idx < 16384) mEnc[idx] = 0u;  // enc floor (< enc of any finite float)
  int z = idx >> 15, rem = idx & 32767;
  int n = rem >> 6, k0 = (rem & 63) << 3;
  const float* W = (z == 0) ? Wq : (z == 1) ? Wk : Wv;
  float sc = (z == 0) ? 0.5f : 1.0f;
  h8 v;
#pragma unroll
  for (int j = 0; j < 8; ++j) v[j] = (_Float16)(W[(k0 + j) * 512 + n] * sc);
  size_t blk = (size_t)((z * 4 + (n >> 7)) * 8 + (k0 >> 6));
  int off = (n & 127) * 64 + ((((k0 >> 3) & 7) ^ (n & 7)) << 3);
  *(h8*)&Wt[blk * 8192 + off] = v;
}

// ---------------- x convert: fp32 -> fp16 IMG-swizzled ----------------
__global__ void xconv_kernel(const float* __restrict__ x, _Float16* __restrict__ Ximg) {
  int idx = blockIdx.x * 256 + threadIdx.x;  // 16384 rows x 64 chunks
  int row = idx >> 6;
  int k0 = (idx & 63) << 3;
  const float* src = &x[(size_t)row * 512 + k0];
  float4 f0 = *(const float4*)src, f1 = *(const float4*)(src + 4);
  h8 v;
  v[0] = (_Float16)f0.x; v[1] = (_Float16)f0.y; v[2] = (_Float16)f0.z; v[3] = (_Float16)f0.w;
  v[4] = (_Float16)f1.x; v[5] = (_Float16)f1.y; v[6] = (_Float16)f1.z; v[7] = (_Float16)f1.w;
  size_t blk = (size_t)((row >> 7) * 8 + (k0 >> 6));  // (b*32+rb) == row>>7
  int off = (row & 127) * 64 + ((((k0 >> 3) & 7) ^ (row & 7)) << 3);
  *(h8*)&Ximg[blk * 8192 + off] = v;
}

// ---------------- QKV projection (qk-structured): [128x128] = Ximg . Wt ----------------
__global__ __launch_bounds__(256, 3)
void proj_kernel(const _Float16* __restrict__ Ximg, const _Float16* __restrict__ Wt,
                 const float* __restrict__ bq, const float* __restrict__ bk,
                 const float* __restrict__ bv,
                 char* __restrict__ Qimg, char* __restrict__ Kimg, char* __restrict__ VTimg) {
  __shared__ _Float16 sMem[16384];
  _Float16* sA = sMem;
  _Float16* sB = sMem + 8192;
  const int tid = threadIdx.x;
  const int wave = tid >> 6, lane = tid & 63;
  const int quad = lane >> 4, lr = lane & 15;
  const int nb4 = blockIdx.x & 3;        // n-block 0..3
  const int z = blockIdx.x >> 2;         // 0..2; z folded in x -> 12 blocks share A-tile
  const int mb = blockIdx.y;             // 0..127 global 128-row block
  const int mbase = mb * 128, nbase = nb4 * 128;
  const int rbase = (wave & 1) * 64, cbase = (wave >> 1) * 64;
  const char* Ab = (const char*)Ximg + ((size_t)(mb * 8)) * 16384;
  const char* Bb = (const char*)Wt + ((size_t)((z * 4 + nb4) * 8)) * 16384;

  f4 acc[4][4];
#pragma unroll
  for (int i = 0; i < 4; ++i)
#pragma unroll
    for (int j = 0; j < 4; ++j) { f4 zz = {0.f, 0.f, 0.f, 0.f}; acc[i][j] = zz; }

#pragma unroll
  for (int j = 0; j < 4; ++j) {  // stage(0)
    gl_lds16(Ab + tid * 16 + j * 4096, (char*)sA + tid * 16 + j * 4096);
    gl_lds16(Bb + tid * 16 + j * 4096, (char*)sB + tid * 16 + j * 4096);
  }

  for (int kt = 0; kt < 8; ++kt) {
    asm volatile("s_waitcnt vmcnt(0)" ::: "memory");
    __builtin_amdgcn_s_barrier();
    __builtin_amdgcn_sched_barrier(0);
    h8 a[4][2], bb[4][2];
#pragma unroll
    for (int ks = 0; ks < 2; ++ks) {
#pragma unroll
      for (int rt = 0; rt < 4; ++rt) {
        const int r = rbase + rt * 16 + lr;
        a[rt][ks] = *(const h8*)&sA[r * 64 + ((((ks << 2) | quad) ^ (lr & 7)) << 3)];
      }
#pragma unroll
      for (int ct = 0; ct < 4; ++ct) {
        const int r = cbase + ct * 16 + lr;
        bb[ct][ks] = *(const h8*)&sB[r * 64 + ((((ks << 2) | quad) ^ (lr & 7)) << 3)];
      }
    }
    asm volatile("s_waitcnt lgkmcnt(0)" ::: "memory");
    __builtin_amdgcn_s_barrier();
    __builtin_amdgcn_sched_barrier(0);
    if (kt < 7) {
#pragma unroll
      for (int j = 0; j < 4; ++j) {
        gl_lds16(Ab + (kt + 1) * 16384 + tid * 16 + j * 4096, (char*)sA + tid * 16 + j * 4096);
        gl_lds16(Bb + (kt + 1) * 16384 + tid * 16 + j * 4096, (char*)sB + tid * 16 + j * 4096);
      }
    }
    __builtin_amdgcn_s_setprio(1);
#pragma unroll
    for (int ks = 0; ks < 2; ++ks)
#pragma unroll
      for (int rt = 0; rt < 4; ++rt)
#pragma unroll
        for (int ct = 0; ct < 4; ++ct)
          acc[rt][ct] = MFMA16(a[rt][ks], bb[ct][ks], acc[rt][ct]);
    __builtin_amdgcn_s_setprio(0);
  }

  // ---- epilogue: bias + swizzled stash -> coalesced image stores ----
  const float* bias = (z == 0) ? bq : (z == 1) ? bk : bv;
  const float bscale = (z == 0) ? 0.5f : 1.0f;
  _Float16* sC = sMem;
  __syncthreads();
#pragma unroll
  for (int ct = 0; ct < 4; ++ct) {
    const int dl = cbase + ct * 16 + lr;
    const float bb = bias[nbase + dl] * bscale;
#pragma unroll
    for (int rt = 0; rt < 4; ++rt) {
#pragma unroll
      for (int r = 0; r < 4; ++r) {
        const int sl = rbase + rt * 16 + quad * 4 + r;
        const _Float16 val = (_Float16)(acc[rt][ct][r] + bb);
        if (z == 2) {  // VT: row=d, k=s
          sC[((sl >> 6) << 13) + dl * 64 + ((((sl >> 3) & 7) ^ (dl & 7)) << 3) + (sl & 7)] = val;
        } else {       // Q/K: row=s, k=d
          sC[((dl >> 6) << 13) + sl * 64 + ((((dl >> 3) & 7) ^ (sl & 7)) << 3) + (dl & 7)] = val;
        }
      }
    }
  }
  __syncthreads();
  const int b_ = mbase >> 12;
  char* dst;
  if (z != 2) {
    char* img = (z == 0) ? Qimg : Kimg;
    dst = img + ((size_t)((b_ * 32 + ((mbase & 4095) >> 7)) * 8 + (nbase >> 6) + (tid >> 7))) * 16384;
  } else {
    dst = VTimg + ((size_t)((b_ * 4 + (nbase >> 7)) * 64 + ((mbase & 4095) >> 6) + (tid >> 7))) * 16384;
  }
  dst += (size_t)(tid & 127) * 128;
#pragma unroll
  for (int k = 0; k < 8; ++k)
    *(int4*)(dst + k * 16) = *(const int4*)&sC[tid * 64 + k * 8];
}

// ---------------- QK GEMM: S[s][t] = Q . K^T -> Simg chunk (+ row-max) ----------------
// Counted-wait pipeline; row-max via LDS combine + 2 full-wave coalesced atomics.
__global__ __launch_bounds__(256, 3)
void qk_kernel(const char* __restrict__ Qimg, const char* __restrict__ Kimg,
               char* __restrict__ S, unsigned* __restrict__ mEnc, int b0, int s0) {
  __shared__ _Float16 sMem[16384];
  _Float16* sA = sMem;
  _Float16* sB = sMem + 8192;
  const int tid = threadIdx.x;
  const int wave = tid >> 6, lane = tid & 63;
  const int quad = lane >> 4, lr = lane & 15;
  const int cb = blockIdx.x;                               // t-block 0..31
  const int rbL = blockIdx.z * gridDim.y + blockIdx.y;     // chunk row-block
  const int b = b0 + blockIdx.z;
  const int rbase = (wave & 1) * 64, cbase = (wave >> 1) * 64;
  const char* Ab = Qimg + ((size_t)((b * 32 + (s0 >> 7) + blockIdx.y) * 8)) * 16384;
  const char* Bb = Kimg + ((size_t)((b * 32 + cb) * 8)) * 16384;

  f4 acc[4][4];
#pragma unroll
  for (int i = 0; i < 4; ++i)
#pragma unroll
    for (int j = 0; j < 4; ++j) { f4 zz = {0.f, 0.f, 0.f, 0.f}; acc[i][j] = zz; }

#pragma unroll
  for (int j = 0; j < 4; ++j) {  // stage(0)
    gl_lds16(Ab + tid * 16 + j * 4096, (char*)sA + tid * 16 + j * 4096);
    gl_lds16(Bb + tid * 16 + j * 4096, (char*)sB + tid * 16 + j * 4096);
  }

  for (int kt = 0; kt < 8; ++kt) {
    asm volatile("s_waitcnt vmcnt(0)" ::: "memory");
    __builtin_amdgcn_s_barrier();
    __builtin_amdgcn_sched_barrier(0);
    h8 a[4][2], bb[4][2];
#pragma unroll
    for (int ks = 0; ks < 2; ++ks) {
#pragma unroll
      for (int rt = 0; rt < 4; ++rt) {
        const int r = rbase + rt * 16 + lr;
        a[rt][ks] = *(const h8*)&sA[r * 64 + ((((ks << 2) | quad) ^ (lr & 7)) << 3)];
      }
#pragma unroll
      for (int ct = 0; ct < 4; ++ct) {
        const int r = cbase + ct * 16 + lr;
        bb[ct][ks] = *(const h8*)&sB[r * 64 + ((((ks << 2) | quad) ^ (lr & 7)) << 3)];
      }
    }
    asm volatile("s_waitcnt lgkmcnt(0)" ::: "memory");
    __builtin_amdgcn_s_barrier();
    __builtin_amdgcn_sched_barrier(0);
    if (kt < 7) {
#pragma unroll
      for (int j = 0; j < 4; ++j) {
        gl_lds16(Ab + (kt + 1) * 16384 + tid * 16 + j * 4096, (char*)sA + tid * 16 + j * 4096);
        gl_lds16(Bb + (kt + 1) * 16384 + tid * 16 + j * 4096, (char*)sB + tid * 16 + j * 4096);
      }
    }
    __builtin_amdgcn_s_setprio(1);
#pragma unroll
    for (int ks = 0; ks < 2; ++ks)
#pragma unroll
      for (int rt = 0; rt < 4; ++rt)
#pragma unroll
        for (int ct = 0; ct < 4; ++ct)
          acc[rt][ct] = MFMA16(a[rt][ks], bb[ct][ks], acc[rt][ct]);
    __builtin_amdgcn_s_setprio(0);
  }

  // ---- row-max: per-wave partials -> LDS combine -> 2 full-wave atomics ----
  float mxv[4][4];
#pragma unroll
  for (int rt = 0; rt < 4; ++rt) {
#pragma unroll
    for (int r = 0; r < 4; ++r) {
      float mx = fmaxf(fmaxf(acc[rt][0][r], acc[rt][1][r]),
                       fmaxf(acc[rt][2][r], acc[rt][3][r]));
      mx = fmaxf(mx, __shfl_xor(mx, 1));
      mx = fmaxf(mx, __shfl_xor(mx, 2));
      mx = fmaxf(mx, __shfl_xor(mx, 4));
      mx = fmaxf(mx, __shfl_xor(mx, 8));
      mxv[rt][r] = mx;
    }
  }
  __syncthreads();                      // K-loop LDS use done; reuse sMem
  float* rmf = (float*)sMem;            // [2][128] partial row-maxes
  if (lr == 0) {
#pragma unroll
    for (int rt = 0; rt < 4; ++rt)
#pragma unroll
      for (int r = 0; r < 4; ++r)
        rmf[(wave >> 1) * 128 + rbase + rt * 16 + quad * 4 + r] = mxv[rt][r];
  }
  __syncthreads();
  if (tid < 128) {
    const float v = fmaxf(rmf[tid], rmf[128 + tid]);
    atomicMax(&mEnc[b * 4096 + s0 + blockIdx.y * 128 + tid], encf(v));
  }
  __syncthreads();                      // rm reads done before stash overwrites

  // epilogue: fp16 stash in Simg layout -> coalesced stores
  _Float16* sC = sMem;
#pragma unroll
  for (int ct = 0; ct < 4; ++ct) {
    const int tl = cbase + ct * 16 + lr;
#pragma unroll
    for (int rt = 0; rt < 4; ++rt) {
#pragma unroll
      for (int r = 0; r < 4; ++r) {
        const int sl = rbase + rt * 16 + quad * 4 + r;
        sC[((tl >> 6) << 13) + sl * 64 + ((((tl >> 3) & 7) ^ (sl & 7)) << 3) + (tl & 7)] =
            (_Float16)acc[rt][ct][r];
      }
    }
  }
  __syncthreads();
  char* dst = S + ((size_t)(rbL * 64 + cb * 2 + (tid >> 7))) * 16384 + (size_t)(tid & 127) * 128;
#pragma unroll
  for (int k = 0; k < 8; ++k)
    *(int4*)(dst + k * 16) = *(const int4*)&sC[tid * 64 + k * 8];
}

// ---------------- PV GEMM, D-merged (BN=512), direct-B: O[64 x 512] = softmax(S) . V ----
// B fragments read DIRECTLY from VTimg (sB was a verbatim img-block copy; offsets
// identical). LDS = sA dbuf only (2x8KB). One barrier + lgkm drain per iteration;
// no vmem drain -> waves de-lockstep, B latency hides under other waves' MFMA.
__global__ __launch_bounds__(512, 2)
void pv_kernel(const char* __restrict__ S, const char* __restrict__ VTimg,
               const unsigned* __restrict__ mEnc, float* __restrict__ out,
               int b0, int s0, int nyb, int nb) {
  __shared__ _Float16 sMem[8192];  // sA dbuf: 2 x (64 rows x 64 k) fp16 = 2 x 8KB
  __shared__ float ls[64];
  const int tid = threadIdx.x;
  const int wave = tid >> 6, lane = tid & 63;
  const int quad = lane >> 4, lr = lane & 15;
  const int flat = blockIdx.x;
  int bL, yl;
  if (nb == 4) { bL = (flat & 7) >> 1; yl = ((flat >> 3) << 1) | (flat & 1); }
  else { bL = flat / nyb; yl = flat - bL * nyb; }
  const int b = b0 + bL;
  const int sbL = bL * nyb + yl;  // chunk-global 64-row block index
  const int rbase = (wave & 1) * 32;
  const int cbase = (wave >> 1) * 128;
  const char* Ab = S + ((size_t)((sbL >> 1) * 64)) * 16384 + (size_t)(sbL & 1) * 8192;
  // per-wave VT base: rb = d>>7 = wave>>1 (d = cbase + ct*16 + lr, ct<8 -> d-cbase<128)
  const _Float16* Bw = (const _Float16*)VTimg + ((size_t)((b * 4 + (wave >> 1)) * 64)) * 8192;

  const int lrow = tid >> 3;
  const float m0 = decf(mEnc[b * 4096 + s0 + yl * 64 + lrow]);
  float rs = 0.f;

  f4 acc[2][8];
#pragma unroll
  for (int i = 0; i < 2; ++i)
#pragma unroll
    for (int j = 0; j < 8; ++j) { f4 zz = {0.f, 0.f, 0.f, 0.f}; acc[i][j] = zz; }

  {  // prologue: exp A(0) -> sA buf0
    h8 ha = __builtin_nontemporal_load((const h8*)(Ab + tid * 16));
    h8 w;
#pragma unroll
    for (int u = 0; u < 8; ++u) { float e = __expf((float)ha[u] - m0); w[u] = (_Float16)e; rs += e; }
    *(h8*)((char*)sMem + tid * 16) = w;
    asm volatile("s_waitcnt lgkmcnt(0)" ::: "memory");
    __builtin_amdgcn_s_barrier();
    __builtin_amdgcn_sched_barrier(0);
  }

  for (int kt = 0; kt < 64; ++kt) {
    const int cur = kt & 1;
    _Float16* sA = sMem + cur * 4096;
    char* sAn = (char*)sMem + (cur ^ 1) * 8192;
    const _Float16* Bk = Bw + (size_t)kt * 8192;  // this K-step's 16KB img block
    const bool more = (kt < 63);
    h8 han;
    if (more) han = __builtin_nontemporal_load((const h8*)(Ab + (kt + 1) * 16384 + tid * 16));
    // ks = 0
    {
      h8 a[2], bbf[8];
#pragma unroll
      for (int rt = 0; rt < 2; ++rt) {
        const int r = rbase + rt * 16 + lr;
        a[rt] = *(const h8*)&sA[r * 64 + (((quad) ^ (lr & 7)) << 3)];
      }
#pragma unroll
      for (int ct = 0; ct < 8; ++ct)
        bbf[ct] = *(const h8*)&Bk[(ct * 16 + lr) * 64 + (((quad) ^ (lr & 7)) << 3)];
      __builtin_amdgcn_s_setprio(1);
#pragma unroll
      for (int rt = 0; rt < 2; ++rt)
#pragma unroll
        for (int ct = 0; ct < 8; ++ct)
          acc[rt][ct] = MFMA16(a[rt], bbf[ct], acc[rt][ct]);
      __builtin_amdgcn_s_setprio(0);
    }
    // exp next-A while MFMA ks0 retires; write into next buf
    if (more) {
      h8 w;
#pragma unroll
      for (int u = 0; u < 8; ++u) { float e = __expf((float)han[u] - m0); w[u] = (_Float16)e; rs += e; }
      *(h8*)(sAn + tid * 16) = w;
    }
    // ks = 1
    {
      h8 a[2], bbf[8];
#pragma unroll
      for (int rt = 0; rt < 2; ++rt) {
        const int r = rbase + rt * 16 + lr;
        a[rt] = *(const h8*)&sA[r * 64 + (((4 | quad) ^ (lr & 7)) << 3)];
      }
#pragma unroll
      for (int ct = 0; ct < 8; ++ct)
        bbf[ct] = *(const h8*)&Bk[(ct * 16 + lr) * 64 + (((4 | quad) ^ (lr & 7)) << 3)];
      __builtin_amdgcn_s_setprio(1);
#pragma unroll
      for (int rt = 0; rt < 2; ++rt)
#pragma unroll
        for (int ct = 0; ct < 8; ++ct)
          acc[rt][ct] = MFMA16(a[rt], bbf[ct], acc[rt][ct]);
      __builtin_amdgcn_s_setprio(0);
    }
    // sA[next] writes visible to all; readers of sA[cur] done
    asm volatile("s_waitcnt lgkmcnt(0)" ::: "memory");
    __builtin_amdgcn_s_barrier();
    __builtin_amdgcn_sched_barrier(0);
  }

  // rowsum: reduce across the 8 threads sharing each staged row, publish via LDS
  rs += __shfl_xor(rs, 1); rs += __shfl_xor(rs, 2); rs += __shfl_xor(rs, 4);
  if ((tid & 7) == 0) ls[lrow] = rs;
  __syncthreads();

  // epilogue: x 1/rowsum, NT scatter stores (64B segments per quad)
#pragma unroll
  for (int rt = 0; rt < 2; ++rt) {
#pragma unroll
    for (int r = 0; r < 4; ++r) {
      const int lrw = rbase + rt * 16 + quad * 4 + r;
      const int srow = s0 + yl * 64 + lrw;
      const float li = 1.0f / ls[lrw];
      float* op = &out[((size_t)b * 4096 + srow) * 512];
#pragma unroll
      for (int ct = 0; ct < 8; ++ct)
        __builtin_nontemporal_store(acc[rt][ct][r] * li, &op[cbase + ct * 16 + lr]);
    }
  }
}

extern "C" void kernel_launch(void* const* d_in, const int* in_sizes, int n_in,
                              void* d_out, int out_size, void* d_ws, size_t ws_size,
                              hipStream_t stream) {
  (void)in_sizes; (void)n_in; (void)out_size;
  const float* x  = (const float*)d_in[0];
  const float* Wq = (const float*)d_in[1];
  const float* bq = (const float*)d_in[2];
  const float* Wk = (const float*)d_in[3];
  const float* bk = (const float*)d_in[4];
  const float* Wv = (const float*)d_in[5];
  const float* bv = (const float*)d_in[6];
  float* out = (float*)d_out;
  char* ws = (char*)d_ws;
  char* Qimg  = ws;
  char* Kimg  = ws + ((size_t)16 << 20);
  char* VTimg = ws + ((size_t)32 << 20);
  _Float16* Wt = (_Float16*)(ws + ((size_t)48 << 20));            // 1.5MB
  unsigned* mEnc = (unsigned*)(ws + ((size_t)50 << 20) - 65536);  // 64KB row-max
  _Float16* Ximg = (_Float16*)(ws + ((size_t)50 << 20));          // 16MB
  char* Simg   = ws + ((size_t)66 << 20);

  wconv_kernel<<<dim3(384), dim3(256), 0, stream>>>(Wq, Wk, Wv, Wt, mEnc);
  xconv_kernel<<<dim3(4096), dim3(256), 0, stream>>>(x, Ximg);
  proj_kernel<<<dim3(12, 128), dim3(256), 0, stream>>>(Ximg, Wt, bq, bk, bv, Qimg, Kimg, VTimg);

  // chunk ladder on ws_size (constant per deployment -> same work every call)
  const size_t avail = ws_size > ((size_t)66 << 20) ? ws_size - ((size_t)66 << 20) : 0;
  int nchunk, nb, Ms;
  if      (avail >= ((size_t)128 << 20)) { nchunk = 1;  nb = 4; Ms = 4096; }
  else if (avail >= ((size_t)64  << 20)) { nchunk = 2;  nb = 2; Ms = 4096; }
  else if (avail >= ((size_t)32  << 20)) { nchunk = 4;  nb = 1; Ms = 4096; }
  else if (avail >= ((size_t)16  << 20)) { nchunk = 8;  nb = 1; Ms = 2048; }
  else if (avail >= ((size_t)8   << 20)) { nchunk = 16; nb = 1; Ms = 1024; }
  else                                   { nchunk = 32; nb = 1; Ms = 512;  }
  const int chunksPerBatch = 4096 / Ms;  // for nb==1 paths; nb>1 has Ms=4096
  const int nyb = Ms / 64;

  for (int c = 0; c < nchunk; ++c) {
    int b0, s0;
    if (nb > 1 || Ms == 4096) { b0 = c * nb; s0 = 0; }
    else { b0 = c / chunksPerBatch; s0 = (c % chunksPerBatch) * Ms; }
    qk_kernel<<<dim3(32, Ms / 128, nb), dim3(256), 0, stream>>>(Qimg, Kimg, Simg, mEnc, b0, s0);
    pv_kernel<<<dim3(nb * nyb), dim3(512), 0, stream>>>(Simg, VTimg, mEnc, out, b0, s0, nyb, nb);
  }
}

// Round 14
// 366.582 us; speedup vs baseline: 1.0467x; 1.0467x over previous
//
#include <hip/hip_runtime.h>

typedef _Float16 h8 __attribute__((ext_vector_type(8)));
typedef float f4 __attribute__((ext_vector_type(4)));

#define MFMA16(a, b, c) __builtin_amdgcn_mfma_f32_16x16x32_f16((a), (b), (c), 0, 0, 0)

__device__ static inline void gl_lds16(const void* g, void* l) {
  __builtin_amdgcn_global_load_lds((const __attribute__((address_space(1))) unsigned int*)g,
                                   (__attribute__((address_space(3))) unsigned int*)l, 16, 0, 0);
}

// Monotone float<->uint encoding for atomicMax on floats (any sign).
__device__ static inline unsigned encf(float f) {
  unsigned u = __float_as_uint(f);
  return (u & 0x80000000u) ? ~u : (u | 0x80000000u);
}
__device__ static inline float decf(unsigned u) {
  return __uint_as_float((u & 0x80000000u) ? (u ^ 0x80000000u) : ~u);
}

// B=4, S=4096, D=512.
// IMG block = 16KB = 128 rows x 64 k fp16; half-offset(r,k) = r*64 + ((((k>>3)&7)^(r&7))<<3) + (k&7).
//  Qimg/Kimg: block(b, rb=s>>7, kc=d>>6) at ((b*32+rb)*8+kc)*16KB        [16MB each]
//  Ximg:      same layout as Qimg (fp16 pre-swizzled x)                  [16MB]
//  VTimg:     block(b, rb=d>>7, kc=s>>6) at ((b*4+rb)*64+kc)*16KB        [16MB]
//  Wt:        block(z, rb=n>>7, kc=k>>6) at ((z*4+rb)*8+kc)*16KB         [1.5MB]
//  Simg(chunk): block(rbL, kc=t>>6) at (rbL*64+kc)*16KB
// Round-14: pv rebuilt with WAVE-PRIVATE B staging (1x8 wave grid: each wave's B
// slice = contiguous 8KB of one img block). Each wave gl_lds's its own slice into a
// private dbuf slot and syncs with its own counted vmcnt (T4 at wave granularity):
// no block-wide vmem drain in the loop; the single barrier drains lgkm (sA exp) only.
// r13's direct-B failed (128B-stride fragment reads, 4x L2 sectors, on MFMA path).

// ---------------- weight convert (+ mEnc zero) ----------------
__global__ void wconv_kernel(const float* __restrict__ Wq, const float* __restrict__ Wk,
                             const float* __restrict__ Wv, _Float16* __restrict__ Wt,
                             unsigned* __restrict__ mEnc) {
  int idx = blockIdx.x * 256 + threadIdx.x;
  if (idx < 16384) mEnc[idx] = 0u;  // enc floor (< enc of any finite float)
  int z = idx >> 15, rem = idx & 32767;
  int n = rem >> 6, k0 = (rem & 63) << 3;
  const float* W = (z == 0) ? Wq : (z == 1) ? Wk : Wv;
  float sc = (z == 0) ? 0.5f : 1.0f;
  h8 v;
#pragma unroll
  for (int j = 0; j < 8; ++j) v[j] = (_Float16)(W[(k0 + j) * 512 + n] * sc);
  size_t blk = (size_t)((z * 4 + (n >> 7)) * 8 + (k0 >> 6));
  int off = (n & 127) * 64 + ((((k0 >> 3) & 7) ^ (n & 7)) << 3);
  *(h8*)&Wt[blk * 8192 + off] = v;
}

// ---------------- x convert: fp32 -> fp16 IMG-swizzled ----------------
__global__ void xconv_kernel(const float* __restrict__ x, _Float16* __restrict__ Ximg) {
  int idx = blockIdx.x * 256 + threadIdx.x;  // 16384 rows x 64 chunks
  int row = idx >> 6;
  int k0 = (idx & 63) << 3;
  const float* src = &x[(size_t)row * 512 + k0];
  float4 f0 = *(const float4*)src, f1 = *(const float4*)(src + 4);
  h8 v;
  v[0] = (_Float16)f0.x; v[1] = (_Float16)f0.y; v[2] = (_Float16)f0.z; v[3] = (_Float16)f0.w;
  v[4] = (_Float16)f1.x; v[5] = (_Float16)f1.y; v[6] = (_Float16)f1.z; v[7] = (_Float16)f1.w;
  size_t blk = (size_t)((row >> 7) * 8 + (k0 >> 6));  // (b*32+rb) == row>>7
  int off = (row & 127) * 64 + ((((k0 >> 3) & 7) ^ (row & 7)) << 3);
  *(h8*)&Ximg[blk * 8192 + off] = v;
}

// ---------------- QKV projection (qk-structured): [128x128] = Ximg . Wt ----------------
__global__ __launch_bounds__(256, 3)
void proj_kernel(const _Float16* __restrict__ Ximg, const _Float16* __restrict__ Wt,
                 const float* __restrict__ bq, const float* __restrict__ bk,
                 const float* __restrict__ bv,
                 char* __restrict__ Qimg, char* __restrict__ Kimg, char* __restrict__ VTimg) {
  __shared__ _Float16 sMem[16384];
  _Float16* sA = sMem;
  _Float16* sB = sMem + 8192;
  const int tid = threadIdx.x;
  const int wave = tid >> 6, lane = tid & 63;
  const int quad = lane >> 4, lr = lane & 15;
  const int nb4 = blockIdx.x & 3;        // n-block 0..3
  const int z = blockIdx.x >> 2;         // 0..2; z folded in x -> 12 blocks share A-tile
  const int mb = blockIdx.y;             // 0..127 global 128-row block
  const int mbase = mb * 128, nbase = nb4 * 128;
  const int rbase = (wave & 1) * 64, cbase = (wave >> 1) * 64;
  const char* Ab = (const char*)Ximg + ((size_t)(mb * 8)) * 16384;
  const char* Bb = (const char*)Wt + ((size_t)((z * 4 + nb4) * 8)) * 16384;

  f4 acc[4][4];
#pragma unroll
  for (int i = 0; i < 4; ++i)
#pragma unroll
    for (int j = 0; j < 4; ++j) { f4 zz = {0.f, 0.f, 0.f, 0.f}; acc[i][j] = zz; }

#pragma unroll
  for (int j = 0; j < 4; ++j) {  // stage(0)
    gl_lds16(Ab + tid * 16 + j * 4096, (char*)sA + tid * 16 + j * 4096);
    gl_lds16(Bb + tid * 16 + j * 4096, (char*)sB + tid * 16 + j * 4096);
  }

  for (int kt = 0; kt < 8; ++kt) {
    asm volatile("s_waitcnt vmcnt(0)" ::: "memory");
    __builtin_amdgcn_s_barrier();
    __builtin_amdgcn_sched_barrier(0);
    h8 a[4][2], bb[4][2];
#pragma unroll
    for (int ks = 0; ks < 2; ++ks) {
#pragma unroll
      for (int rt = 0; rt < 4; ++rt) {
        const int r = rbase + rt * 16 + lr;
        a[rt][ks] = *(const h8*)&sA[r * 64 + ((((ks << 2) | quad) ^ (lr & 7)) << 3)];
      }
#pragma unroll
      for (int ct = 0; ct < 4; ++ct) {
        const int r = cbase + ct * 16 + lr;
        bb[ct][ks] = *(const h8*)&sB[r * 64 + ((((ks << 2) | quad) ^ (lr & 7)) << 3)];
      }
    }
    asm volatile("s_waitcnt lgkmcnt(0)" ::: "memory");
    __builtin_amdgcn_s_barrier();
    __builtin_amdgcn_sched_barrier(0);
    if (kt < 7) {
#pragma unroll
      for (int j = 0; j < 4; ++j) {
        gl_lds16(Ab + (kt + 1) * 16384 + tid * 16 + j * 4096, (char*)sA + tid * 16 + j * 4096);
        gl_lds16(Bb + (kt + 1) * 16384 + tid * 16 + j * 4096, (char*)sB + tid * 16 + j * 4096);
      }
    }
    __builtin_amdgcn_s_setprio(1);
#pragma unroll
    for (int ks = 0; ks < 2; ++ks)
#pragma unroll
      for (int rt = 0; rt < 4; ++rt)
#pragma unroll
        for (int ct = 0; ct < 4; ++ct)
          acc[rt][ct] = MFMA16(a[rt][ks], bb[ct][ks], acc[rt][ct]);
    __builtin_amdgcn_s_setprio(0);
  }

  // ---- epilogue: bias + swizzled stash -> coalesced image stores ----
  const float* bias = (z == 0) ? bq : (z == 1) ? bk : bv;
  const float bscale = (z == 0) ? 0.5f : 1.0f;
  _Float16* sC = sMem;
  __syncthreads();
#pragma unroll
  for (int ct = 0; ct < 4; ++ct) {
    const int dl = cbase + ct * 16 + lr;
    const float bb = bias[nbase + dl] * bscale;
#pragma unroll
    for (int rt = 0; rt < 4; ++rt) {
#pragma unroll
      for (int r = 0; r < 4; ++r) {
        const int sl = rbase + rt * 16 + quad * 4 + r;
        const _Float16 val = (_Float16)(acc[rt][ct][r] + bb);
        if (z == 2) {  // VT: row=d, k=s
          sC[((sl >> 6) << 13) + dl * 64 + ((((sl >> 3) & 7) ^ (dl & 7)) << 3) + (sl & 7)] = val;
        } else {       // Q/K: row=s, k=d
          sC[((dl >> 6) << 13) + sl * 64 + ((((dl >> 3) & 7) ^ (sl & 7)) << 3) + (dl & 7)] = val;
        }
      }
    }
  }
  __syncthreads();
  const int b_ = mbase >> 12;
  char* dst;
  if (z != 2) {
    char* img = (z == 0) ? Qimg : Kimg;
    dst = img + ((size_t)((b_ * 32 + ((mbase & 4095) >> 7)) * 8 + (nbase >> 6) + (tid >> 7))) * 16384;
  } else {
    dst = VTimg + ((size_t)((b_ * 4 + (nbase >> 7)) * 64 + ((mbase & 4095) >> 6) + (tid >> 7))) * 16384;
  }
  dst += (size_t)(tid & 127) * 128;
#pragma unroll
  for (int k = 0; k < 8; ++k)
    *(int4*)(dst + k * 16) = *(const int4*)&sC[tid * 64 + k * 8];
}

// ---------------- QK GEMM: S[s][t] = Q . K^T -> Simg chunk (+ row-max) ----------------
// Counted-wait pipeline; row-max via LDS combine + 2 full-wave coalesced atomics.
__global__ __launch_bounds__(256, 3)
void qk_kernel(const char* __restrict__ Qimg, const char* __restrict__ Kimg,
               char* __restrict__ S, unsigned* __restrict__ mEnc, int b0, int s0) {
  __shared__ _Float16 sMem[16384];
  _Float16* sA = sMem;
  _Float16* sB = sMem + 8192;
  const int tid = threadIdx.x;
  const int wave = tid >> 6, lane = tid & 63;
  const int quad = lane >> 4, lr = lane & 15;
  const int cb = blockIdx.x;                               // t-block 0..31
  const int rbL = blockIdx.z * gridDim.y + blockIdx.y;     // chunk row-block
  const int b = b0 + blockIdx.z;
  const int rbase = (wave & 1) * 64, cbase = (wave >> 1) * 64;
  const char* Ab = Qimg + ((size_t)((b * 32 + (s0 >> 7) + blockIdx.y) * 8)) * 16384;
  const char* Bb = Kimg + ((size_t)((b * 32 + cb) * 8)) * 16384;

  f4 acc[4][4];
#pragma unroll
  for (int i = 0; i < 4; ++i)
#pragma unroll
    for (int j = 0; j < 4; ++j) { f4 zz = {0.f, 0.f, 0.f, 0.f}; acc[i][j] = zz; }

#pragma unroll
  for (int j = 0; j < 4; ++j) {  // stage(0)
    gl_lds16(Ab + tid * 16 + j * 4096, (char*)sA + tid * 16 + j * 4096);
    gl_lds16(Bb + tid * 16 + j * 4096, (char*)sB + tid * 16 + j * 4096);
  }

  for (int kt = 0; kt < 8; ++kt) {
    asm volatile("s_waitcnt vmcnt(0)" ::: "memory");
    __builtin_amdgcn_s_barrier();
    __builtin_amdgcn_sched_barrier(0);
    h8 a[4][2], bb[4][2];
#pragma unroll
    for (int ks = 0; ks < 2; ++ks) {
#pragma unroll
      for (int rt = 0; rt < 4; ++rt) {
        const int r = rbase + rt * 16 + lr;
        a[rt][ks] = *(const h8*)&sA[r * 64 + ((((ks << 2) | quad) ^ (lr & 7)) << 3)];
      }
#pragma unroll
      for (int ct = 0; ct < 4; ++ct) {
        const int r = cbase + ct * 16 + lr;
        bb[ct][ks] = *(const h8*)&sB[r * 64 + ((((ks << 2) | quad) ^ (lr & 7)) << 3)];
      }
    }
    asm volatile("s_waitcnt lgkmcnt(0)" ::: "memory");
    __builtin_amdgcn_s_barrier();
    __builtin_amdgcn_sched_barrier(0);
    if (kt < 7) {
#pragma unroll
      for (int j = 0; j < 4; ++j) {
        gl_lds16(Ab + (kt + 1) * 16384 + tid * 16 + j * 4096, (char*)sA + tid * 16 + j * 4096);
        gl_lds16(Bb + (kt + 1) * 16384 + tid * 16 + j * 4096, (char*)sB + tid * 16 + j * 4096);
      }
    }
    __builtin_amdgcn_s_setprio(1);
#pragma unroll
    for (int ks = 0; ks < 2; ++ks)
#pragma unroll
      for (int rt = 0; rt < 4; ++rt)
#pragma unroll
        for (int ct = 0; ct < 4; ++ct)
          acc[rt][ct] = MFMA16(a[rt][ks], bb[ct][ks], acc[rt][ct]);
    __builtin_amdgcn_s_setprio(0);
  }

  // ---- row-max: per-wave partials -> LDS combine -> 2 full-wave atomics ----
  float mxv[4][4];
#pragma unroll
  for (int rt = 0; rt < 4; ++rt) {
#pragma unroll
    for (int r = 0; r < 4; ++r) {
      float mx = fmaxf(fmaxf(acc[rt][0][r], acc[rt][1][r]),
                       fmaxf(acc[rt][2][r], acc[rt][3][r]));
      mx = fmaxf(mx, __shfl_xor(mx, 1));
      mx = fmaxf(mx, __shfl_xor(mx, 2));
      mx = fmaxf(mx, __shfl_xor(mx, 4));
      mx = fmaxf(mx, __shfl_xor(mx, 8));
      mxv[rt][r] = mx;
    }
  }
  __syncthreads();                      // K-loop LDS use done; reuse sMem
  float* rmf = (float*)sMem;            // [2][128] partial row-maxes
  if (lr == 0) {
#pragma unroll
    for (int rt = 0; rt < 4; ++rt)
#pragma unroll
      for (int r = 0; r < 4; ++r)
        rmf[(wave >> 1) * 128 + rbase + rt * 16 + quad * 4 + r] = mxv[rt][r];
  }
  __syncthreads();
  if (tid < 128) {
    const float v = fmaxf(rmf[tid], rmf[128 + tid]);
    atomicMax(&mEnc[b * 4096 + s0 + blockIdx.y * 128 + tid], encf(v));
  }
  __syncthreads();                      // rm reads done before stash overwrites

  // epilogue: fp16 stash in Simg layout -> coalesced stores
  _Float16* sC = sMem;
#pragma unroll
  for (int ct = 0; ct < 4; ++ct) {
    const int tl = cbase + ct * 16 + lr;
#pragma unroll
    for (int rt = 0; rt < 4; ++rt) {
#pragma unroll
      for (int r = 0; r < 4; ++r) {
        const int sl = rbase + rt * 16 + quad * 4 + r;
        sC[((tl >> 6) << 13) + sl * 64 + ((((tl >> 3) & 7) ^ (sl & 7)) << 3) + (tl & 7)] =
            (_Float16)acc[rt][ct][r];
      }
    }
  }
  __syncthreads();
  char* dst = S + ((size_t)(rbL * 64 + cb * 2 + (tid >> 7))) * 16384 + (size_t)(tid & 127) * 128;
#pragma unroll
  for (int k = 0; k < 8; ++k)
    *(int4*)(dst + k * 16) = *(const int4*)&sC[tid * 64 + k * 8];
}

// ---------------- PV GEMM, D-merged (BN=512), wave-private B: O = softmax(S) . V ----
// 1x8 wave grid: wave w owns cols [64w,64w+64) -> its B slice per kt is the contiguous
// 8KB at (w&1)*8192 of img block rb=w>>1. Each wave stages its slice into a PRIVATE
// dbuf LDS slot and waits with its own counted vmcnt (no block vmem drain). Block
// barrier only for sA (exp) dbuf, lgkm drain only. A issued before B each iter so the
// exp's implicit wait is vmcnt(8), leaving next B tile in flight.
__global__ __launch_bounds__(512, 2)
void pv_kernel(const char* __restrict__ S, const char* __restrict__ VTimg,
               const unsigned* __restrict__ mEnc, float* __restrict__ out,
               int b0, int s0, int nyb, int nb) {
  __shared__ _Float16 sMem[73728];  // sA dbuf 2x4096 elem; sB 8 waves x 2 bufs x 4096 elem
  __shared__ float ls[64];
  const int tid = threadIdx.x;
  const int wave = tid >> 6, lane = tid & 63;
  const int quad = lane >> 4, lr = lane & 15;
  const int flat = blockIdx.x;
  int bL, yl;
  if (nb == 4) { bL = (flat & 7) >> 1; yl = ((flat >> 3) << 1) | (flat & 1); }
  else { bL = flat / nyb; yl = flat - bL * nyb; }
  const int b = b0 + bL;
  const int sbL = bL * nyb + yl;  // chunk-global 64-row block index
  const int cbase = wave * 64;    // 1x8 grid: wave owns cols [64w, 64w+64)
  const char* Ab = S + ((size_t)((sbL >> 1) * 64)) * 16384 + (size_t)(sbL & 1) * 8192;
  // wave's B source: img block rb=wave>>1, byte half (wave&1)*8192, stepped by kt
  const char* Bw = VTimg + ((size_t)((b * 4 + (wave >> 1)) * 64)) * 16384 + (wave & 1) * 8192;
  _Float16* const sBw = sMem + 8192 + wave * 8192;  // private: [2 bufs][4096 elem]

  const int lrow = tid >> 3;
  const float m0 = decf(mEnc[b * 4096 + s0 + yl * 64 + lrow]);
  float rs = 0.f;

  f4 acc[4][4];
#pragma unroll
  for (int i = 0; i < 4; ++i)
#pragma unroll
    for (int j = 0; j < 4; ++j) { f4 zz = {0.f, 0.f, 0.f, 0.f}; acc[i][j] = zz; }

  {  // prologue: A(0) first, B(0) -> sBw buf0; exp A(0) -> sA buf0
    h8 ha = __builtin_nontemporal_load((const h8*)(Ab + tid * 16));
    __builtin_amdgcn_sched_barrier(0);
#pragma unroll
    for (int j = 0; j < 8; ++j)
      gl_lds16(Bw + j * 1024 + lane * 16, (char*)sBw + j * 1024 + lane * 16);
    __builtin_amdgcn_sched_barrier(0);
    h8 w;
#pragma unroll
    for (int u = 0; u < 8; ++u) { float e = __expf((float)ha[u] - m0); w[u] = (_Float16)e; rs += e; }
    *(h8*)((char*)sMem + tid * 16) = w;
    asm volatile("s_waitcnt lgkmcnt(0)" ::: "memory");
    __builtin_amdgcn_s_barrier();
    __builtin_amdgcn_sched_barrier(0);
  }

  for (int kt = 0; kt < 64; ++kt) {
    const int cur = kt & 1;
    _Float16* sA = sMem + cur * 4096;
    const _Float16* sBc = sBw + cur * 4096;
    const bool more = (kt < 63);
    h8 han;
    if (more) {  // A(kt+1) FIRST (oldest of the new 9 -> exp waits vmcnt(8))
      han = __builtin_nontemporal_load((const h8*)(Ab + (kt + 1) * 16384 + tid * 16));
      __builtin_amdgcn_sched_barrier(0);
#pragma unroll
      for (int j = 0; j < 8; ++j)
        gl_lds16(Bw + (size_t)(kt + 1) * 16384 + j * 1024 + lane * 16,
                 (char*)sBw + (cur ^ 1) * 8192 + j * 1024 + lane * 16);
      asm volatile("s_waitcnt vmcnt(9)" ::: "memory");  // B(kt) landed (9 newer in flight)
    } else {
      asm volatile("s_waitcnt vmcnt(0)" ::: "memory");  // last tile: drain B(63)
    }
    __builtin_amdgcn_sched_barrier(0);
    // ks = 0
    {
      h8 a[4], bbf[4];
#pragma unroll
      for (int rt = 0; rt < 4; ++rt) {
        const int r = rt * 16 + lr;
        a[rt] = *(const h8*)&sA[r * 64 + (((quad) ^ (lr & 7)) << 3)];
      }
#pragma unroll
      for (int ct = 0; ct < 4; ++ct)
        bbf[ct] = *(const h8*)&sBc[(ct * 16 + lr) * 64 + (((quad) ^ (lr & 7)) << 3)];
      __builtin_amdgcn_s_setprio(1);
#pragma unroll
      for (int rt = 0; rt < 4; ++rt)
#pragma unroll
        for (int ct = 0; ct < 4; ++ct)
          acc[rt][ct] = MFMA16(a[rt], bbf[ct], acc[rt][ct]);
      __builtin_amdgcn_s_setprio(0);
    }
    // exp next-A while MFMA ks0 retires (implicit wait vmcnt(8): B(kt+1) stays in flight)
    if (more) {
      h8 w;
#pragma unroll
      for (int u = 0; u < 8; ++u) { float e = __expf((float)han[u] - m0); w[u] = (_Float16)e; rs += e; }
      *(h8*)((char*)sMem + (cur ^ 1) * 8192 + tid * 16) = w;
    }
    // ks = 1
    {
      h8 a[4], bbf[4];
#pragma unroll
      for (int rt = 0; rt < 4; ++rt) {
        const int r = rt * 16 + lr;
        a[rt] = *(const h8*)&sA[r * 64 + (((4 | quad) ^ (lr & 7)) << 3)];
      }
#pragma unroll
      for (int ct = 0; ct < 4; ++ct)
        bbf[ct] = *(const h8*)&sBc[(ct * 16 + lr) * 64 + (((4 | quad) ^ (lr & 7)) << 3)];
      __builtin_amdgcn_s_setprio(1);
#pragma unroll
      for (int rt = 0; rt < 4; ++rt)
#pragma unroll
        for (int ct = 0; ct < 4; ++ct)
          acc[rt][ct] = MFMA16(a[rt], bbf[ct], acc[rt][ct]);
      __builtin_amdgcn_s_setprio(0);
    }
    // block sync for sA dbuf only: exp writes visible, readers of sA[cur] done
    asm volatile("s_waitcnt lgkmcnt(0)" ::: "memory");
    __builtin_amdgcn_s_barrier();
    __builtin_amdgcn_sched_barrier(0);
  }

  // rowsum: reduce across the 8 threads sharing each staged row, publish via LDS
  rs += __shfl_xor(rs, 1); rs += __shfl_xor(rs, 2); rs += __shfl_xor(rs, 4);
  if ((tid & 7) == 0) ls[lrow] = rs;
  __syncthreads();

  // epilogue: x 1/rowsum, NT scatter stores (64B segments per quad)
#pragma unroll
  for (int rt = 0; rt < 4; ++rt) {
#pragma unroll
    for (int r = 0; r < 4; ++r) {
      const int lrw = rt * 16 + quad * 4 + r;
      const int srow = s0 + yl * 64 + lrw;
      const float li = 1.0f / ls[lrw];
      float* op = &out[((size_t)b * 4096 + srow) * 512];
#pragma unroll
      for (int ct = 0; ct < 4; ++ct)
        __builtin_nontemporal_store(acc[rt][ct][r] * li, &op[cbase + ct * 16 + lr]);
    }
  }
}

extern "C" void kernel_launch(void* const* d_in, const int* in_sizes, int n_in,
                              void* d_out, int out_size, void* d_ws, size_t ws_size,
                              hipStream_t stream) {
  (void)in_sizes; (void)n_in; (void)out_size;
  const float* x  = (const float*)d_in[0];
  const float* Wq = (const float*)d_in[1];
  const float* bq = (const float*)d_in[2];
  const float* Wk = (const float*)d_in[3];
  const float* bk = (const float*)d_in[4];
  const float* Wv = (const float*)d_in[5];
  const float* bv = (const float*)d_in[6];
  float* out = (float*)d_out;
  char* ws = (char*)d_ws;
  char* Qimg  = ws;
  char* Kimg  = ws + ((size_t)16 << 20);
  char* VTimg = ws + ((size_t)32 << 20);
  _Float16* Wt = (_Float16*)(ws + ((size_t)48 << 20));            // 1.5MB
  unsigned* mEnc = (unsigned*)(ws + ((size_t)50 << 20) - 65536);  // 64KB row-max
  _Float16* Ximg = (_Float16*)(ws + ((size_t)50 << 20));          // 16MB
  char* Simg   = ws + ((size_t)66 << 20);

  wconv_kernel<<<dim3(384), dim3(256), 0, stream>>>(Wq, Wk, Wv, Wt, mEnc);
  xconv_kernel<<<dim3(4096), dim3(256), 0, stream>>>(x, Ximg);
  proj_kernel<<<dim3(12, 128), dim3(256), 0, stream>>>(Ximg, Wt, bq, bk, bv, Qimg, Kimg, VTimg);

  // chunk ladder on ws_size (constant per deployment -> same work every call)
  const size_t avail = ws_size > ((size_t)66 << 20) ? ws_size - ((size_t)66 << 20) : 0;
  int nchunk, nb, Ms;
  if      (avail >= ((size_t)128 << 20)) { nchunk = 1;  nb = 4; Ms = 4096; }
  else if (avail >= ((size_t)64  << 20)) { nchunk = 2;  nb = 2; Ms = 4096; }
  else if (avail >= ((size_t)32  << 20)) { nchunk = 4;  nb = 1; Ms = 4096; }
  else if (avail >= ((size_t)16  << 20)) { nchunk = 8;  nb = 1; Ms = 2048; }
  else if (avail >= ((size_t)8   << 20)) { nchunk = 16; nb = 1; Ms = 1024; }
  else                                   { nchunk = 32; nb = 1; Ms = 512;  }
  const int chunksPerBatch = 4096 / Ms;  // for nb==1 paths; nb>1 has Ms=4096
  const int nyb = Ms / 64;

  for (int c = 0; c < nchunk; ++c) {
    int b0, s0;
    if (nb > 1 || Ms == 4096) { b0 = c * nb; s0 = 0; }
    else { b0 = c / chunksPerBatch; s0 = (c % chunksPerBatch) * Ms; }
    qk_kernel<<<dim3(32, Ms / 128, nb), dim3(256), 0, stream>>>(Qimg, Kimg, Simg, mEnc, b0, s0);
    pv_kernel<<<dim3(nb * nyb), dim3(512), 0, stream>>>(Simg, VTimg, mEnc, out, b0, s0, nyb, nb);
  }
}